// Round 8
// baseline (35.395 us; speedup 1.0000x reference)
//
#include <hip/hip_runtime.h>

#define IHH 306
#define KW 7
#define OUTC 10
#define FH 300
#define NPIX (FH * FH)            // 90000
#define KK (KW * KW)              // 49
#define BLK 512
#define GRID 176                  // <= 1 block/CU, all co-resident
#define NROWS 21                  // 10 hit-abs, 10 miss-abs, 1 x-sum
#define OUT4 472500               // 1890000 / 4
#define POOLED_END 90000
#define HIT_END 990000
#define CHUNK4 2685               // ceil(OUT4 / GRID)

// ws layout:
//   0     : partials[NROWS][GRID] floats (14784 B)
//   16384 : done[GRID] ints, 4B stride (704 B)   -- memset 0 each call
//
// Fence-free symmetric protocol: all cross-block data moves via agent-scope
// RELAXED atomics (bypass non-coherent caches to the coherence point).
// Ordering: __syncthreads() drains vmcnt before s_barrier, so the done-flag
// store issued after it cannot precede the partials stores. Every block
// polls all flags and reduces the whole table itself -- no publish hop,
// no special block, no RMW, no cache-maintenance fences.

#define AL(p)    __hip_atomic_load((p), __ATOMIC_RELAXED, __HIP_MEMORY_SCOPE_AGENT)
#define AS(p, v) __hip_atomic_store((p), (v), __ATOMIC_RELAXED, __HIP_MEMORY_SCOPE_AGENT)

__global__ __launch_bounds__(BLK) void k_fused(
    const float* __restrict__ x,
    const float* __restrict__ kh,
    const float* __restrict__ km,
    float* __restrict__ partials,
    int* __restrict__ done,
    float4* __restrict__ out)
{
    __shared__ float2 s_k[KK * OUTC];   // [tap][o] = (kh, km)
    __shared__ float s_red[BLK / 64][NROWS];
    __shared__ float s_part[NROWS][16];
    __shared__ float s_ks[2 * OUTC];
    __shared__ float s_o[3 * OUTC];     // [0..9]=pooled, [10..19]=Fh, [20..29]=Fm

    const int t = threadIdx.x;
    const int b = blockIdx.x;

    // ---- Phase 1: per-block partial sums -------------------------------
    for (int i = t; i < KK * OUTC; i += BLK) {
        const int tap = i / OUTC;
        const int o = i - tap * OUTC;
        s_k[i] = make_float2(kh[o * KK + tap], km[o * KK + tap]);
    }
    __syncthreads();

    float ah[OUTC], am[OUTC];
    float sx = 0.0f;
#pragma unroll
    for (int o = 0; o < OUTC; ++o) { ah[o] = 0.0f; am[o] = 0.0f; }

    const int p = b * BLK + t;
    if (p < NPIX) {
        const int i = p / FH;
        const int j = p - i * FH;
        const float* xr = x + i * IHH + j;
        for (int u = 0; u < KW; ++u) {
            for (int v = 0; v < KW; ++v) {
                const float xv = xr[u * IHH + v];
                sx += xv;
                const float2* wk = &s_k[(u * KW + v) * OUTC];
#pragma unroll
                for (int o = 0; o < OUTC; ++o) {
                    const float2 w = wk[o];
                    ah[o] += fabsf(xv - w.x);
                    am[o] += fabsf(xv - w.y);
                }
            }
        }
    }

    const int lane = t & 63;
    const int wave = t >> 6;
    float vals[NROWS];
#pragma unroll
    for (int o = 0; o < OUTC; ++o) { vals[o] = ah[o]; vals[OUTC + o] = am[o]; }
    vals[2 * OUTC] = sx;
#pragma unroll
    for (int r = 0; r < NROWS; ++r) {
        float v = vals[r];
#pragma unroll
        for (int s = 32; s > 0; s >>= 1) v += __shfl_xor(v, s);
        if (lane == 0) s_red[wave][r] = v;
    }
    __syncthreads();
    if (t < NROWS) {
        float s = 0.0f;
#pragma unroll
        for (int w = 0; w < BLK / 64; ++w) s += s_red[w][t];
        AS(&partials[t * GRID + b], s);     // coherence-point store
    }
    __syncthreads();                        // vmcnt(0) drain: stores complete
    if (t == 0) AS(&done[b], 1);            // flag cannot precede data

    // ---- ksums from LDS-staged weights (wave 7, overlaps the poll) -----
    if (t >= 448 && t < 448 + 2 * OUTC) {
        const int a = t - 448;
        const int o = (a < OUTC) ? a : a - OUTC;
        float s = 0.0f;
        for (int tap = 0; tap < KK; ++tap) {
            const float2 w = s_k[tap * OUTC + o];
            s += (a < OUTC) ? w.x : w.y;
        }
        s_ks[a] = s;
    }

    // ---- Symmetric barrier: poll all flags (waves 0-2) -----------------
    if (t < GRID) {
        while (AL(&done[t]) == 0) __builtin_amdgcn_s_sleep(1);
    }
    __syncthreads();

    // ---- Every block reduces the whole table ---------------------------
    if (t < NROWS * 16) {
        const int r = t >> 4;
        const int s16 = t & 15;
        float acc = 0.0f;
        for (int c = s16; c < GRID; c += 16)
            acc += AL(&partials[r * GRID + c]);
        s_part[r][s16] = acc;
    }
    __syncthreads();
    if (t < NROWS) {
        float f = 0.0f;
#pragma unroll
        for (int s = 0; s < 16; ++s) f += s_part[t][s];
        s_part[t][0] = f;
    }
    __syncthreads();
    if (t < OUTC) {
        const float Sx = s_part[2 * OUTC][0];
        const float Ah = s_part[t][0];
        const float Am = s_part[OUTC + t][0];
        const float Fh = 0.5f * ((Sx - (float)NPIX * s_ks[t]) - Ah);
        const float Fm = 0.5f * ((Sx - (float)NPIX * s_ks[OUTC + t]) + Am);
        s_o[t] = Fh - Fm;
        s_o[OUTC + t] = Fh;
        s_o[2 * OUTC + t] = Fm;
    }
    __syncthreads();

    // ---- Fill ----------------------------------------------------------
    const int start = b * CHUNK4;
    const int stop = min(start + CHUNK4, OUT4);
    for (int i4 = start + t; i4 < stop; i4 += BLK) {
        const int base = i4 * 4;
        float v;
        if (base < POOLED_END) {
            v = s_o[base / 9000];                         // pooled
        } else if (base < HIT_END) {
            v = s_o[OUTC + (base - POOLED_END) / 90000];  // F_hit
        } else {
            v = s_o[2 * OUTC + (base - HIT_END) / 90000]; // F_miss
        }
        out[i4] = make_float4(v, v, v, v);
    }
}

extern "C" void kernel_launch(void* const* d_in, const int* in_sizes, int n_in,
                              void* d_out, int out_size, void* d_ws, size_t ws_size,
                              hipStream_t stream) {
    const float* x  = (const float*)d_in[0];
    const float* kh = (const float*)d_in[1];
    const float* km = (const float*)d_in[2];
    float4* out = (float4*)d_out;

    float* partials = (float*)d_ws;                      // 14784 B
    int*   done     = (int*)((char*)d_ws + 16384);       // 176 x 4B

    (void)hipMemsetAsync(done, 0, GRID * sizeof(int), stream);
    k_fused<<<GRID, BLK, 0, stream>>>(x, kh, km, partials, done, out);
}